// Round 3
// baseline (345.373 us; speedup 1.0000x reference)
//
#include <hip/hip_runtime.h>
#include <hip/hip_bf16.h>
#include <stdint.h>

#define B_ROWS 32768
#define DIM 512
#define BM 128
#define BN 128
#define BK 64
#define THREADS 512
#define WBUF 49152   // 3 mats * 128 cols * 128 B
#define NKT 16

typedef __attribute__((ext_vector_type(8))) __bf16 bf16x8;
typedef __attribute__((ext_vector_type(4))) float f32x4;
typedef __attribute__((ext_vector_type(4))) unsigned int uint4v;

__device__ static inline unsigned short f2bf(float f) {
    unsigned int u = __builtin_bit_cast(unsigned int, f);
    u += 0x7fffu + ((u >> 16) & 1u);
    return (unsigned short)(u >> 16);
}

__device__ static inline void load_lds_16B(const void* g, void* lds) {
    __builtin_amdgcn_global_load_lds(
        (const __attribute__((address_space(1))) unsigned int*)g,
        (__attribute__((address_space(3))) unsigned int*)lds,
        16, 0, 0);
}

// ---------------- prep: weights -> Wt[3][n=512][k=1024] bf16, k XOR-swizzled ----
__global__ void prep_weights(const float* __restrict__ Wu_x, const float* __restrict__ Wu_h,
                             const float* __restrict__ Wr_x, const float* __restrict__ Wr_h,
                             const float* __restrict__ Wc_x, const float* __restrict__ Wc_h,
                             unsigned short* __restrict__ Wt) {
    __shared__ float tile[32][33];
    const int t = blockIdx.z;
    const int k0 = blockIdx.x * 32;
    const int n0 = blockIdx.y * 32;
    const float* Wx = (t == 0) ? Wu_x : (t == 1) ? Wr_x : Wc_x;
    const float* Wh = (t == 0) ? Wu_h : (t == 1) ? Wr_h : Wc_h;
    const int tid = threadIdx.x;
    const int c = tid & 31, r0 = tid >> 5;
#pragma unroll
    for (int i = 0; i < 4; ++i) {
        int kl = r0 + i * 8;
        int k = k0 + kl;
        int n = n0 + c;
        float v = (k < 512) ? Wx[(size_t)k * 512 + n] : Wh[(size_t)(k - 512) * 512 + n];
        tile[kl][c] = v;
    }
    __syncthreads();
#pragma unroll
    for (int i = 0; i < 4; ++i) {
        int nl = r0 + i * 8;
        int kl = c;
        int n = n0 + nl, k = k0 + kl;
        Wt[(size_t)t * (512 * 1024) + (size_t)n * 1024 + (k ^ ((n & 7) << 3))] =
            f2bf(tile[kl][nl]);
    }
}

// ---------------- prep: A = [x|h] -> bf16 row-major [32768][1024] ----------------
__global__ __launch_bounds__(512) void prep_A(const float* __restrict__ x,
                                              const float* __restrict__ h,
                                              unsigned short* __restrict__ Apack) {
    const size_t i = (size_t)blockIdx.x * 512 + threadIdx.x;  // chunk of 8 elems
    const int row = (int)(i >> 7);
    const int c = (int)(i & 127);
    const float* src = (c < 64) ? (x + (size_t)row * 512 + c * 8)
                                : (h + (size_t)row * 512 + (c - 64) * 8);
    float4 f0 = *(const float4*)(src + 0);
    float4 f1 = *(const float4*)(src + 4);
    uint4v p;
    p.x = f2bf(f0.x) | ((unsigned)f2bf(f0.y) << 16);
    p.y = f2bf(f0.z) | ((unsigned)f2bf(f0.w) << 16);
    p.z = f2bf(f1.x) | ((unsigned)f2bf(f1.y) << 16);
    p.w = f2bf(f1.z) | ((unsigned)f2bf(f1.w) << 16);
    *(uint4v*)((char*)Apack + i * 16) = p;
}

// ---------------- main: W triple-buffer LDS, A in regs, counted vmcnt ----------
__global__ __launch_bounds__(THREADS, 2) void augru_main(
    const float* __restrict__ h, const float* __restrict__ att,
    const unsigned short* __restrict__ Wt, const unsigned short* __restrict__ Apack,
    const float* __restrict__ bu, const float* __restrict__ br,
    const float* __restrict__ bc, float* __restrict__ out) {
    extern __shared__ char smem[];   // 3 * 48 KB
    const int tid = threadIdx.x;
    const int lane = tid & 63;
    const int wid = tid >> 6;
    const int wm = wid >> 2;
    const int wn = wid & 3;
    const int id = blockIdx.x;
    const int wg = (id & 7) * 128 + (id >> 3);   // XCD-bijective (1024 % 8 == 0)
    const int nb = wg & 3;
    const int mb = wg >> 2;
    const int cl = lane & 15;
    const int kg = lane >> 4;

    f32x4 accU[4][2], accR[4][2], accCx[4][2], accCh[4][2];
#pragma unroll
    for (int i = 0; i < 4; ++i)
#pragma unroll
        for (int j = 0; j < 2; ++j) {
            accU[i][j] = (f32x4)(0.f);
            accR[i][j] = (f32x4)(0.f);
            accCx[i][j] = (f32x4)(0.f);
            accCh[i][j] = (f32x4)(0.f);
        }

    // per-lane A base: row = mb*128 + wm*64 + cl, byte-in-row = kg*16
    const char* aBase = (const char*)Apack
        + (size_t)(mb * 128 + wm * 64 + cl) * 2048 + kg * 16;
    bf16x8 a[2][4];

    auto loadA = [&](int kt) {
#pragma unroll
        for (int ks = 0; ks < 2; ++ks)
#pragma unroll
            for (int mi = 0; mi < 4; ++mi)
                a[ks][mi] = __builtin_bit_cast(
                    bf16x8, *(const uint4v*)(aBase + (size_t)mi * 32768 + kt * 128 + ks * 64));
    };

    auto stageW = [&](int buf, int kt) {
#pragma unroll
        for (int it = 0; it < 6; ++it) {
            const int b = it * 8192 + tid * 16;
            const int t = b >> 14;
            const int n_l = (b & 16383) >> 7;
            const int off = b & 127;
            const char* g = (const char*)Wt + ((size_t)t << 20)
                + (size_t)(nb * 128 + n_l) * 2048 + kt * 128 + off;
            load_lds_16B(g, smem + buf * WBUF + it * 8192 + wid * 1024);
        }
    };

    // prologue: W(0), W(1) in flight; A(0) in regs-to-be
    stageW(0, 0);
    stageW(1, 1);
    loadA(0);

    auto body = [&](int kt, f32x4(&accC)[4][2], bool last) {
        if (last)
            asm volatile("s_waitcnt vmcnt(8)" ::: "memory");   // only A(kt) after W(kt)
        else
            asm volatile("s_waitcnt vmcnt(14)" ::: "memory");  // W(kt+1)+A(kt) after W(kt)
        __builtin_amdgcn_s_barrier();  // all waves: W(kt) landed, buf(kt-1) reads done
        if (kt + 2 < NKT) stageW((kt + 2) % 3, kt + 2);
        const char* wB = smem + (kt % 3) * WBUF;
        bf16x8 bb[2][3][2];
#pragma unroll
        for (int ks = 0; ks < 2; ++ks) {
            const int kbyte = ks * 64 + kg * 16;
#pragma unroll
            for (int t = 0; t < 3; ++t)
#pragma unroll
                for (int ni = 0; ni < 2; ++ni) {
                    const int col = wn * 32 + ni * 16 + cl;
                    bb[ks][t][ni] = __builtin_bit_cast(
                        bf16x8, *(const uint4v*)(wB + t * 16384
                            + ((col * 128 + kbyte) ^ ((col & 7) << 4))));
                }
        }
        __builtin_amdgcn_s_setprio(1);
#pragma unroll
        for (int ks = 0; ks < 2; ++ks) {
#pragma unroll
            for (int ni = 0; ni < 2; ++ni) {
#pragma unroll
                for (int mi = 0; mi < 4; ++mi)
                    accU[mi][ni] = __builtin_amdgcn_mfma_f32_16x16x32_bf16(
                        a[ks][mi], bb[ks][0][ni], accU[mi][ni], 0, 0, 0);
#pragma unroll
                for (int mi = 0; mi < 4; ++mi)
                    accR[mi][ni] = __builtin_amdgcn_mfma_f32_16x16x32_bf16(
                        a[ks][mi], bb[ks][1][ni], accR[mi][ni], 0, 0, 0);
#pragma unroll
                for (int mi = 0; mi < 4; ++mi)
                    accC[mi][ni] = __builtin_amdgcn_mfma_f32_16x16x32_bf16(
                        a[ks][mi], bb[ks][2][ni], accC[mi][ni], 0, 0, 0);
            }
        }
        __builtin_amdgcn_s_setprio(0);
        if (kt + 1 < NKT) loadA(kt + 1);   // WAR on a[] keeps this after the MFMAs
    };

    for (int kt = 0; kt < 8; ++kt) body(kt, accCx, false);
    for (int kt = 8; kt < 15; ++kt) body(kt, accCh, false);
    body(15, accCh, true);

    // ---- fused epilogue ----
#pragma unroll
    for (int ni = 0; ni < 2; ++ni) {
        const int col = nb * BN + wn * 32 + ni * 16 + cl;
        const float bU = bu[col];
        const float bR = br[col];
        const float bC = bc[col];
#pragma unroll
        for (int mi = 0; mi < 4; ++mi) {
#pragma unroll
            for (int j = 0; j < 4; ++j) {
                const int row = mb * BM + wm * 64 + mi * 16 + kg * 4 + j;
                const float up = accU[mi][ni][j] + bU;
                const float rp = accR[mi][ni][j] + bR;
                const float u = 1.f / (1.f + __expf(-up));
                const float r = 1.f / (1.f + __expf(-rp));
                const float cc = tanhf(accCx[mi][ni][j] + bC + r * accCh[mi][ni][j]);
                const float aa = att[row];
                const float hv = h[(size_t)row * 512 + col];
                const float u_ = aa * u;
                out[(size_t)row * 512 + col] = (1.f - u_) * hv + u_ * cc;
            }
        }
    }
}

extern "C" void kernel_launch(void* const* d_in, const int* in_sizes, int n_in,
                              void* d_out, int out_size, void* d_ws, size_t ws_size,
                              hipStream_t stream) {
    const float* x    = (const float*)d_in[0];
    const float* h    = (const float*)d_in[1];
    const float* att  = (const float*)d_in[2];
    const float* Wu_x = (const float*)d_in[3];
    const float* bu   = (const float*)d_in[4];
    const float* Wu_h = (const float*)d_in[5];
    const float* Wr_x = (const float*)d_in[6];
    const float* br   = (const float*)d_in[7];
    const float* Wr_h = (const float*)d_in[8];
    const float* Wc_x = (const float*)d_in[9];
    const float* bc   = (const float*)d_in[10];
    const float* Wc_h = (const float*)d_in[11];
    unsigned short* Wt = (unsigned short*)d_ws;                        // 3 MB @ 0
    unsigned short* Apack = (unsigned short*)((char*)d_ws + (4 << 20)); // 64 MB @ 4MB
    float* out = (float*)d_out;

    prep_weights<<<dim3(32, 16, 3), 256, 0, stream>>>(Wu_x, Wu_h, Wr_x, Wr_h, Wc_x, Wc_h, Wt);
    prep_A<<<dim3(8192), 512, 0, stream>>>(x, h, Apack);

    hipFuncSetAttribute((const void*)augru_main,
                        hipFuncAttributeMaxDynamicSharedMemorySize, 3 * WBUF);
    augru_main<<<dim3(1024), THREADS, 3 * WBUF, stream>>>(
        h, att, Wt, Apack, bu, br, bc, out);
}